// Round 16
// baseline (80.585 us; speedup 1.0000x reference)
//
#include <hip/hip_runtime.h>
#include <math.h>

// Problem constants (match reference)
constexpr int NB = 32, NM = 64, NK = 8400, NC = 80, NT = 15;
constexpr int NQ = 4, KQ = 2100;       // k split into 4 quarters of 2100
constexpr float FEPS = 1e-7f;

typedef float f32x4 __attribute__((ext_vector_type(4)));   // NT-store compatible

// Output layout: [tso | tgt_bboxes | assign | overlaps | fg], all float32
constexpr size_t OUT_TSO = 0;
constexpr size_t OUT_TGT = (size_t)NB * NK * NC;            // 21504000
constexpr size_t OUT_ASN = OUT_TGT + (size_t)NB * NK * 4;   // 22579200
constexpr size_t OUT_OVL = OUT_ASN + (size_t)NB * NM * NK;  // 39782400
constexpr size_t OUT_FG  = OUT_OVL + (size_t)NB * NM * NK;  // 56985600

constexpr int NCOMP = NB * NM * NQ;    // 8192 compute blocks
constexpr int NFILL = 2048;            // fill blocks (every 5th block)
constexpr int N4A  = (int)(OUT_TGT / 4);   // tso end (f32x4 units)
constexpr int ASN4 = (int)(OUT_ASN / 4);   // tgt end / assign begin
constexpr int OVL4 = (int)(OUT_OVL / 4);   // assign end (tso+tgt+asn span)
constexpr int FG4s = (int)(OUT_FG / 4);    // fg begin
constexpr int FG4c = NB * NK / 4;          // fg count = 67200
constexpr int TOT4 = OVL4 + FG4c;          // 10,012,800 f32x4 to default-fill
constexpr int S4   = 960;                  // slice per compute block
constexpr int F4   = TOT4 - NCOMP * S4;    // 2,148,480 for fill blocks

// default-fill: tso=0, tgt=gtb[b][0] (argmax of all-zero col -> 0), asn=0, fg=0
static __device__ __forceinline__ void zfill(float* out,
                                             const float* __restrict__ gtb,
                                             int j0, int j1, int step)
{
  f32x4* o4 = (f32x4*)out;
  const f32x4 z = {0.f, 0.f, 0.f, 0.f};
  for (int j = j0; j < j1; j += step) {
    const int a = (j < OVL4) ? j : FG4s + (j - OVL4);
    f32x4 v = z;
    if (a >= N4A && a < ASN4)        // tgt region: one f32x4 per (b,k)
      v = *(const f32x4*)(gtb + (size_t)((a - N4A) / NK) * NM * 4);
    __builtin_nontemporal_store(v, &o4[a]);
  }
}

// ---------------------------------------------------------------------------
// kZ: workspace init (mikey=0, fg0=0, flag=0). Must precede kAF (atomicMax).
// ---------------------------------------------------------------------------
__global__ __launch_bounds__(256) void kZ(unsigned long long* __restrict__ mikey,
                                          int* __restrict__ fg0,
                                          int* __restrict__ flag)
{
  const int n = NB * NK;
  const int tid = blockIdx.x * 256 + threadIdx.x;
  for (int i = tid; i < n; i += gridDim.x * 256) { mikey[i] = 0ULL; fg0[i] = 0; }
  if (tid == 0) *flag = 0;
}

// ---------------------------------------------------------------------------
// kAF: 10240 blocks, role-specialized (every 5th = fill, rest = compute).
// NO device fences / cross-block sync — visibility via kernel boundary.
//  fill   : streaming NT default-fill (tso/asn/fg zeros + tgt=gtb[b][0])
//  compute: one block per (b,m,quarter):
//    HEAD  : issue this block's 15 KB default-fill slice (~4 NT stores/thread)
//            BEFORE pass 1 — stores drain under pass-1/2 latency
//    pass 1: zero LDS ov tile + point-in-box -> ushort positive list
//    pass 2: CIoU on positives -> s_ov, mi atomicMax key, (am,idx) candidates
//    flush : dense f32x4 NT overlaps write from s_ov
//    tail  : wave 0 emits per-quarter top-15 -> candk (n<=15: direct write,
//            order-free for kA2's key-max merge); waves 1-3 exit after flush
// ---------------------------------------------------------------------------
__global__ __launch_bounds__(256) void kAF(
    const float* __restrict__ points, const float* __restrict__ gt_bboxes,
    const int* __restrict__ gt_labels, const float* __restrict__ pred_bboxes,
    const float* __restrict__ pred_scores, const int* __restrict__ gt_mask,
    float* __restrict__ out, unsigned long long* __restrict__ candk,
    float* __restrict__ ovmaxq, unsigned long long* __restrict__ mikey)
{
  __shared__ __align__(16) float s_ov[KQ];       // 8.4 KB dense overlaps tile
  __shared__ unsigned short s_pos[KQ];           // 4.2 KB positive local-idx list
  __shared__ float s_cv[KQ];                     // 8.4 KB candidate am values
  __shared__ unsigned short s_ci[KQ];            // 4.2 KB candidate local idx
  __shared__ int   s_np, s_cnt;
  __shared__ float s_m[4];

  const int bx = blockIdx.x;
  const int t  = threadIdx.x;

  // ---- fill role: every 5th block default-fills [0, F4) ----
  if ((bx % 5) == 4) {
    zfill(out, gt_bboxes, (bx / 5) * 256 + t, F4, NFILL * 256);
    return;
  }

  // ---- compute role ----
  const int cidx = bx - (bx + 1) / 5;            // 0..8191
  const int bm = cidx >> 2;                      // 4 quarter blocks adjacent
  const int q  = cidx & 3;
  const int b  = bm >> 6;
  const int m  = bm & 63;
  const int wid = t >> 6, lane = t & 63;
  const int kbeg = q * KQ;
  const int sbase = F4 + cidx * S4;              // this block's fill slice

  // HEAD: issue the default-fill slice now; drains under pass-1/2 latency
  zfill(out, gt_bboxes, sbase + t, sbase + S4, 256);

  unsigned long long* ck = candk + (size_t)(bm * NQ + q) * NT;
  float* ovl_out = out + OUT_OVL + (size_t)bm * NK;
  f32x4* ov4 = (f32x4*)(ovl_out + kbeg);

  const int maskv = gt_mask[bm];
  if (!maskv) {
    const f32x4 z = {0.f, 0.f, 0.f, 0.f};
    for (int idx = t; idx < KQ / 4; idx += 256)
      __builtin_nontemporal_store(z, &ov4[idx]);
    if (t == 0) ovmaxq[bm * NQ + q] = 0.f;
    if (wid == 0 && lane < NT) ck[lane] = 0ULL;
    return;
  }
  if (t == 0) { s_np = 0; s_cnt = 0; }
  __syncthreads();

  const float4 g = *(const float4*)(gt_bboxes + (size_t)bm * 4);
  const int   label = gt_labels[bm];
  const float2* pts = (const float2*)points;

  // pass 1: zero ov tile + point-in-box (diff.max(-1)<1e-6, exact f32 subs)
  #pragma unroll
  for (int j = 0; j < 9; ++j) {
    const int idx = j * 256 + t;
    if (idx < KQ) {
      s_ov[idx] = 0.f;
      const int k = kbeg + idx;
      float2 p = pts[k];
      float dmax = fmaxf(fmaxf(g.x - p.x, g.y - p.y),
                         fmaxf(p.x - g.z, p.y - g.w));
      if (dmax < 1e-6f) {
        int e = atomicAdd(&s_np, 1);
        s_pos[e] = (unsigned short)idx;
      }
    }
  }
  __syncthreads();
  const int np = s_np;

  const float4* pb = (const float4*)(pred_bboxes + (size_t)b * NK * 4);
  const float*  ps = pred_scores + (size_t)b * NK * NC;
  unsigned long long* mk = mikey + (size_t)b * NK;

  const float w1 = g.z - g.x, h1 = g.w - g.y;
  const float at1 = atanf(w1 / (h1 + FEPS));
  const float area1 = w1 * h1;
  const float CV = (float)(4.0 / (M_PI * M_PI));
  const float ONE_EPS = (float)(1.0 + 1e-7);

  float lmax = 0.f;
  for (int e = t; e < np; e += 256) {
    const int li = s_pos[e];
    const int k = kbeg + li;
    float4 qb = pb[k];
    float w2 = qb.z - qb.x, h2 = qb.w - qb.y;
    float iw = fmaxf(fminf(g.z, qb.z) - fmaxf(g.x, qb.x), 0.f);
    float ih = fmaxf(fminf(g.w, qb.w) - fmaxf(g.y, qb.y), 0.f);
    float inter = iw * ih;
    float uni = area1 + w2 * h2 - inter + FEPS;
    float iou = inter / uni;
    float cw = fmaxf(g.z, qb.z) - fminf(g.x, qb.x);
    float ch = fmaxf(g.w, qb.w) - fminf(g.y, qb.y);
    float c2 = cw * cw + ch * ch + FEPS;
    float ex = qb.x + qb.z - g.x - g.z;
    float ey = qb.y + qb.w - g.y - g.w;
    float rho2 = (ex * ex + ey * ey) * 0.25f;
    float dat = atanf(w2 / (h2 + FEPS)) - at1;
    float v = CV * dat * dat;
    float alpha = v / (v - iou + ONE_EPS);
    float ciou = iou - (rho2 / c2 + alpha * v);
    float ov = fmaxf(ciou, 0.f);
    if (ov > 0.f) {
      s_ov[li] = ov;
      unsigned long long key =
          ((unsigned long long)__float_as_uint(ov) << 32) |
          (unsigned long long)(NM - 1 - m);             // value desc, first-m tie
      atomicMax(&mk[k], key);
      lmax = fmaxf(lmax, ov);
      float ts = ps[(size_t)k * NC + label];
      float o2 = ov * ov;
      float am = ts * (o2 * o2 * o2);                   // ts**1 * ov**6
      if (am > 1e-9f) {                                 // below cutoff never selected
        int p2 = atomicAdd(&s_cnt, 1);
        s_cv[p2] = am;
        s_ci[p2] = (unsigned short)li;
      }
    }
  }

  // partial row-max of overlaps
  float mv = lmax;
  #pragma unroll
  for (int d = 1; d < 64; d <<= 1) mv = fmaxf(mv, __shfl_xor(mv, d));
  if (lane == 0) s_m[wid] = mv;
  __syncthreads();   // finalizes s_ov, s_cv/s_ci, s_m
  if (t == 0)
    ovmaxq[bm * NQ + q] = fmaxf(fmaxf(s_m[0], s_m[1]), fmaxf(s_m[2], s_m[3]));

  // dense coalesced overlaps flush (zeros + positives)
  const f32x4* sv4 = (const f32x4*)s_ov;
  for (int idx = t; idx < KQ / 4; idx += 256)
    __builtin_nontemporal_store(sv4[idx], &ov4[idx]);

  if (wid != 0) return;         // waves 1-3 done (fill already issued at head)

  const int n = s_cnt;

  // fast path: n <= 15 candidates -> emit all, no selection needed.
  // candk slot order is irrelevant: kA2's merge extracts by key max, and all
  // downstream results depend only on the key-ordered set (deterministic).
  if (n <= NT) {
    if (lane < NT) {
      unsigned long long key = 0ULL;
      if (lane < n) {
        const int gk = kbeg + s_ci[lane];
        key = ((unsigned long long)__float_as_uint(s_cv[lane]) << 32) |
              (unsigned long long)(0xFFFFFFFFu - (unsigned)gk);
      }
      ck[lane] = key;
    }
    return;
  }

  // slow path: per-quarter top-15 by iterative argmax
  // key = fbits(am)<<32 | (0xFFFF - local_idx); local order == global order
  unsigned long long bkey = 0; int bslot = -1;
  for (int e = lane; e < n; e += 64) {
    float v = s_cv[e];
    unsigned long long key =
        ((unsigned long long)__float_as_uint(v) << 32) |
        (unsigned long long)(0xFFFFu - s_ci[e]);
    if (key > bkey) { bkey = key; bslot = e; }
  }
  for (int it = 0; it < NT; ++it) {
    unsigned long long wkey = bkey;
    #pragma unroll
    for (int d = 1; d < 64; d <<= 1) {
      unsigned long long ok = __shfl_xor(wkey, d);
      if (ok > wkey) wkey = ok;
    }
    if (lane == 0) {
      // re-expand to global-k key for the cross-quarter merge in kA2
      const int gk = kbeg + (int)(0xFFFFu - (unsigned)(wkey & 0xFFFFu));
      ck[it] = (wkey & 0xFFFFFFFF00000000ull) |
               (unsigned long long)(0xFFFFFFFFu - (unsigned)gk);
    }
    if (bkey == wkey) {         // unique winner (local idx unique in low bits)
      s_cv[bslot] = -1.f;
      bkey = 0; bslot = -1;
      for (int e = lane; e < n; e += 64) {
        float v = s_cv[e];
        if (v >= 0.f) {
          unsigned long long key =
              ((unsigned long long)__float_as_uint(v) << 32) |
              (unsigned long long)(0xFFFFu - s_ci[e]);
          if (key > bkey) { bkey = key; bslot = e; }
        }
      }
    }
  }
}

// ---------------------------------------------------------------------------
// kA2: one wave per (b,m): merge 4x15 quarter candidates -> global top-15
// (selection by packed key: value desc, idx asc — order within candk slots
// is irrelevant), fg0/flag atomics, ovmax merge. Kernel boundary provides
// cross-XCD visibility of candk.
// ---------------------------------------------------------------------------
__global__ __launch_bounds__(64) void kA2(
    const unsigned long long* __restrict__ candk,
    const float* __restrict__ ovmaxq, float* __restrict__ ovmaxp,
    int* __restrict__ tki, float* __restrict__ tkv,
    int* __restrict__ fg0, int* __restrict__ flag)
{
  const int bm = blockIdx.x;
  const int b  = bm >> 6;
  const int lane = threadIdx.x;

  if (lane == 0) {
    const float* om = ovmaxq + bm * NQ;
    ovmaxp[bm] = fmaxf(fmaxf(om[0], om[1]), fmaxf(om[2], om[3]));
  }

  unsigned long long mkey = (lane < NQ * NT)
      ? candk[(size_t)bm * NQ * NT + lane] : 0ULL;
  unsigned long long mywin = 0ULL;
  int nf = 0;
  for (int it = 0; it < NT; ++it) {
    unsigned long long wkey = mkey;
    #pragma unroll
    for (int d = 1; d < 64; d <<= 1) {
      unsigned long long ok = __shfl_xor(wkey, d);
      if (ok > wkey) wkey = ok;
    }
    if (wkey == 0) break;
    if (lane == it) mywin = wkey;                // round-it winner kept in lane it
    if (mkey == wkey) mkey = 0ULL;               // unique winner consumed
    nf = it + 1;
  }

  if (lane < NT) {
    if (lane < nf) {
      const int fi = (int)(0xFFFFFFFFu - (unsigned)mywin);
      tki[bm * NT + lane] = fi;
      tkv[bm * NT + lane] = __uint_as_float((unsigned)(mywin >> 32));
      int old = atomicAdd(&fg0[(size_t)b * NK + fi], 1);
      if (old >= 1) atomicOr(flag, 1);
    } else {
      tki[bm * NT + lane] = -1;
      tkv[bm * NT + lane] = 0.f;
    }
  }
}

// ---------------------------------------------------------------------------
// kFS: one wave per (b,m). Keep-filter (mikey + flag), 16-lane rowmax, then
// <=15 scattered writes each of {assign=1, tso=sval, fg=1, tgt=gtb[bm]}.
// Post-filter assignment is unique per k => race-free. Defaults (fg=0,
// tgt=gtb[b][0], tso=0, assign=0) were produced by kAF's fill.
// ---------------------------------------------------------------------------
__global__ __launch_bounds__(64) void kFS(
    const float* __restrict__ gt_bboxes, const int* __restrict__ gt_labels,
    const int* __restrict__ tki, const float* __restrict__ tkv,
    const float* __restrict__ ovmaxp, const unsigned long long* __restrict__ mikey,
    const int* __restrict__ flagp, float* __restrict__ out)
{
  const int bm = blockIdx.x;
  const int b  = bm >> 6;
  const int m  = bm & 63;
  const int lane = threadIdx.x;
  const int flag = *flagp;

  int idx = -1; float v = 0.f; bool keep = false;
  if (lane < NT) {
    idx = tki[bm * NT + lane];
    if (idx >= 0) {
      v = tkv[bm * NT + lane];
      keep = true;
      if (flag) {
        unsigned long long key = mikey[(size_t)b * NK + idx];
        keep = (NM - 1 - (int)(key & 0xFFFFFFFFull)) == m;   // key>0 for valid
      }
    }
  }
  // post-filter row max of am (reduce over the 16-lane group holding lanes 0-14)
  float r = keep ? v : 0.f;
  #pragma unroll
  for (int d = 1; d < 16; d <<= 1) r = fmaxf(r, __shfl_xor(r, d));

  if (keep) {
    const float sval = v / (r + 1e-9f) * ovmaxp[bm];   // same op order as before
    out[OUT_ASN + (size_t)(b * NM + m) * NK + idx] = 1.f;
    out[OUT_TSO + (size_t)(b * NK + idx) * NC + gt_labels[bm]] = sval;
    out[OUT_FG + (size_t)b * NK + idx] = 1.f;
    *(f32x4*)(out + OUT_TGT + (size_t)(b * NK + idx) * 4) =
        *(const f32x4*)(gt_bboxes + (size_t)bm * 4);
  }
}

// ---------------------------------------------------------------------------
extern "C" void kernel_launch(void* const* d_in, const int* in_sizes, int n_in,
                              void* d_out, int out_size, void* d_ws, size_t ws_size,
                              hipStream_t stream)
{
  const float* points      = (const float*)d_in[0];
  const float* gt_bboxes   = (const float*)d_in[1];
  const int*   gt_labels   = (const int*)d_in[2];
  const float* pred_bboxes = (const float*)d_in[3];
  const float* pred_scores = (const float*)d_in[4];
  const int*   gt_mask     = (const int*)d_in[5];
  float* out = (float*)d_out;

  char* ws = (char*)d_ws;
  unsigned long long* mikey = (unsigned long long*)ws; ws += (size_t)NB * NK * 8;
  int*   fg0    = (int*)ws;    ws += (size_t)NB * NK * 4;
  int*   flag   = (int*)ws;    ws += 256;
  unsigned long long* candk = (unsigned long long*)ws;
                               ws += (size_t)NB * NM * NQ * NT * 8;
  int*   tki    = (int*)ws;    ws += (size_t)NB * NM * NT * 4;
  float* tkv    = (float*)ws;  ws += (size_t)NB * NM * NT * 4;
  float* ovmaxp = (float*)ws;  ws += (size_t)NB * NM * 4;
  float* ovmaxq = (float*)ws;  ws += (size_t)NB * NM * NQ * 4;

  // ws init (must precede kAF's mikey atomics)
  kZ<<<1024, 256, 0, stream>>>(mikey, fg0, flag);

  // fused default-fill + compute (no cross-block sync inside)
  kAF<<<NCOMP + NFILL, 256, 0, stream>>>(points, gt_bboxes, gt_labels,
                                         pred_bboxes, pred_scores, gt_mask,
                                         out, candk, ovmaxq, mikey);

  kA2<<<NB * NM, 64, 0, stream>>>(candk, ovmaxq, ovmaxp, tki, tkv, fg0, flag);

  kFS<<<NB * NM, 64, 0, stream>>>(gt_bboxes, gt_labels, tki, tkv, ovmaxp,
                                  mikey, flag, out);
}

// Round 17
// 80.426 us; speedup vs baseline: 1.0020x; 1.0020x over previous
//
#include <hip/hip_runtime.h>
#include <math.h>

// Problem constants (match reference)
constexpr int NB = 32, NM = 64, NK = 8400, NC = 80, NT = 15;
constexpr int NQ = 4, KQ = 2100;       // k split into 4 quarters of 2100
constexpr float FEPS = 1e-7f;

typedef float f32x4 __attribute__((ext_vector_type(4)));   // NT-store compatible

// Output layout: [tso | tgt_bboxes | assign | overlaps | fg], all float32
constexpr size_t OUT_TSO = 0;
constexpr size_t OUT_TGT = (size_t)NB * NK * NC;            // 21504000
constexpr size_t OUT_ASN = OUT_TGT + (size_t)NB * NK * 4;   // 22579200
constexpr size_t OUT_OVL = OUT_ASN + (size_t)NB * NM * NK;  // 39782400
constexpr size_t OUT_FG  = OUT_OVL + (size_t)NB * NM * NK;  // 56985600

constexpr int NCOMP = NB * NM * NQ;    // 8192 compute blocks (no fill role)
constexpr int N4A  = (int)(OUT_TGT / 4);   // tso end (f32x4 units)
constexpr int ASN4 = (int)(OUT_ASN / 4);   // tgt end / assign begin
constexpr int OVL4 = (int)(OUT_OVL / 4);   // assign end (tso+tgt+asn span)
constexpr int FG4s = (int)(OUT_FG / 4);    // fg begin
constexpr int FG4c = NB * NK / 4;          // fg count = 67200
constexpr int TOT4 = OVL4 + FG4c;          // 10,012,800 f32x4 to default-fill
constexpr int S4   = 1222;                 // slice per compute block (tail)
constexpr int F4   = TOT4 - NCOMP * S4;    // 2176 residual -> kZ

// default-fill: tso=0, tgt=gtb[b][0] (argmax of all-zero col -> 0), asn=0, fg=0
static __device__ __forceinline__ void zfill(float* out,
                                             const float* __restrict__ gtb,
                                             int j0, int j1, int step)
{
  f32x4* o4 = (f32x4*)out;
  const f32x4 z = {0.f, 0.f, 0.f, 0.f};
  for (int j = j0; j < j1; j += step) {
    const int a = (j < OVL4) ? j : FG4s + (j - OVL4);
    f32x4 v = z;
    if (a >= N4A && a < ASN4)        // tgt region: one f32x4 per (b,k)
      v = *(const f32x4*)(gtb + (size_t)((a - N4A) / NK) * NM * 4);
    __builtin_nontemporal_store(v, &o4[a]);
  }
}

// ---------------------------------------------------------------------------
// kZ: workspace init (mikey=0, fg0=0, flag=0) + residual F4 default-fill.
// Must precede kAF (atomicMax ordering via kernel boundary).
// ---------------------------------------------------------------------------
__global__ __launch_bounds__(256) void kZ(float* __restrict__ out,
                                          const float* __restrict__ gtb,
                                          unsigned long long* __restrict__ mikey,
                                          int* __restrict__ fg0,
                                          int* __restrict__ flag)
{
  const int n = NB * NK;
  const int tid = blockIdx.x * 256 + threadIdx.x;
  for (int i = tid; i < n; i += gridDim.x * 256) { mikey[i] = 0ULL; fg0[i] = 0; }
  zfill(out, gtb, tid, F4, gridDim.x * 256);   // 2176 f32x4, one iter
  if (tid == 0) *flag = 0;
}

// ---------------------------------------------------------------------------
// kAF: 8192 blocks, one per (b,m,quarter). NO role split, no cross-block sync.
//    pass 1: zero LDS ov tile + point-in-box -> ushort positive list
//    pass 2: CIoU on positives -> s_ov, mi atomicMax key, (am,idx) candidates
//    flush : dense f32x4 NT overlaps write from s_ov
//    tail  : wave 0 emits per-quarter top-15 -> candk (n<=15: direct write,
//            order-free for kA2's key-max merge) WHILE waves 1-3 default-fill
//            this block's 19.5 KB slice (store-issue overlap)
// ---------------------------------------------------------------------------
__global__ __launch_bounds__(256) void kAF(
    const float* __restrict__ points, const float* __restrict__ gt_bboxes,
    const int* __restrict__ gt_labels, const float* __restrict__ pred_bboxes,
    const float* __restrict__ pred_scores, const int* __restrict__ gt_mask,
    float* __restrict__ out, unsigned long long* __restrict__ candk,
    float* __restrict__ ovmaxq, unsigned long long* __restrict__ mikey)
{
  __shared__ __align__(16) float s_ov[KQ];       // 8.4 KB dense overlaps tile
  __shared__ unsigned short s_pos[KQ];           // 4.2 KB positive local-idx list
  __shared__ float s_cv[KQ];                     // 8.4 KB candidate am values
  __shared__ unsigned short s_ci[KQ];            // 4.2 KB candidate local idx
  __shared__ int   s_np, s_cnt;
  __shared__ float s_m[4];

  const int cidx = blockIdx.x;                   // 0..8191
  const int t  = threadIdx.x;
  const int bm = cidx >> 2;                      // 4 quarter blocks adjacent
  const int q  = cidx & 3;
  const int b  = bm >> 6;
  const int m  = bm & 63;
  const int wid = t >> 6, lane = t & 63;
  const int kbeg = q * KQ;
  const int sbase = F4 + cidx * S4;              // this block's fill slice

  unsigned long long* ck = candk + (size_t)(bm * NQ + q) * NT;
  float* ovl_out = out + OUT_OVL + (size_t)bm * NK;
  f32x4* ov4 = (f32x4*)(ovl_out + kbeg);

  const int maskv = gt_mask[bm];
  if (!maskv) {
    const f32x4 z = {0.f, 0.f, 0.f, 0.f};
    for (int idx = t; idx < KQ / 4; idx += 256)
      __builtin_nontemporal_store(z, &ov4[idx]);
    if (wid != 0) { zfill(out, gt_bboxes, sbase + (t - 64), sbase + S4, 192); return; }
    if (t == 0) ovmaxq[bm * NQ + q] = 0.f;
    if (lane < NT) ck[lane] = 0ULL;
    return;
  }
  if (t == 0) { s_np = 0; s_cnt = 0; }
  __syncthreads();

  const float4 g = *(const float4*)(gt_bboxes + (size_t)bm * 4);
  const int   label = gt_labels[bm];
  const float2* pts = (const float2*)points;

  // pass 1: zero ov tile + point-in-box (diff.max(-1)<1e-6, exact f32 subs)
  #pragma unroll
  for (int j = 0; j < 9; ++j) {
    const int idx = j * 256 + t;
    if (idx < KQ) {
      s_ov[idx] = 0.f;
      const int k = kbeg + idx;
      float2 p = pts[k];
      float dmax = fmaxf(fmaxf(g.x - p.x, g.y - p.y),
                         fmaxf(p.x - g.z, p.y - g.w));
      if (dmax < 1e-6f) {
        int e = atomicAdd(&s_np, 1);
        s_pos[e] = (unsigned short)idx;
      }
    }
  }
  __syncthreads();
  const int np = s_np;

  const float4* pb = (const float4*)(pred_bboxes + (size_t)b * NK * 4);
  const float*  ps = pred_scores + (size_t)b * NK * NC;
  unsigned long long* mk = mikey + (size_t)b * NK;

  const float w1 = g.z - g.x, h1 = g.w - g.y;
  const float at1 = atanf(w1 / (h1 + FEPS));
  const float area1 = w1 * h1;
  const float CV = (float)(4.0 / (M_PI * M_PI));
  const float ONE_EPS = (float)(1.0 + 1e-7);

  float lmax = 0.f;
  for (int e = t; e < np; e += 256) {
    const int li = s_pos[e];
    const int k = kbeg + li;
    float4 qb = pb[k];
    float w2 = qb.z - qb.x, h2 = qb.w - qb.y;
    float iw = fmaxf(fminf(g.z, qb.z) - fmaxf(g.x, qb.x), 0.f);
    float ih = fmaxf(fminf(g.w, qb.w) - fmaxf(g.y, qb.y), 0.f);
    float inter = iw * ih;
    float uni = area1 + w2 * h2 - inter + FEPS;
    float iou = inter / uni;
    float cw = fmaxf(g.z, qb.z) - fminf(g.x, qb.x);
    float ch = fmaxf(g.w, qb.w) - fminf(g.y, qb.y);
    float c2 = cw * cw + ch * ch + FEPS;
    float ex = qb.x + qb.z - g.x - g.z;
    float ey = qb.y + qb.w - g.y - g.w;
    float rho2 = (ex * ex + ey * ey) * 0.25f;
    float dat = atanf(w2 / (h2 + FEPS)) - at1;
    float v = CV * dat * dat;
    float alpha = v / (v - iou + ONE_EPS);
    float ciou = iou - (rho2 / c2 + alpha * v);
    float ov = fmaxf(ciou, 0.f);
    if (ov > 0.f) {
      s_ov[li] = ov;
      unsigned long long key =
          ((unsigned long long)__float_as_uint(ov) << 32) |
          (unsigned long long)(NM - 1 - m);             // value desc, first-m tie
      atomicMax(&mk[k], key);
      lmax = fmaxf(lmax, ov);
      float ts = ps[(size_t)k * NC + label];
      float o2 = ov * ov;
      float am = ts * (o2 * o2 * o2);                   // ts**1 * ov**6
      if (am > 1e-9f) {                                 // below cutoff never selected
        int p2 = atomicAdd(&s_cnt, 1);
        s_cv[p2] = am;
        s_ci[p2] = (unsigned short)li;
      }
    }
  }

  // partial row-max of overlaps
  float mv = lmax;
  #pragma unroll
  for (int d = 1; d < 64; d <<= 1) mv = fmaxf(mv, __shfl_xor(mv, d));
  if (lane == 0) s_m[wid] = mv;
  __syncthreads();   // finalizes s_ov, s_cv/s_ci, s_m
  if (t == 0)
    ovmaxq[bm * NQ + q] = fmaxf(fmaxf(s_m[0], s_m[1]), fmaxf(s_m[2], s_m[3]));

  // dense coalesced overlaps flush (zeros + positives)
  const f32x4* sv4 = (const f32x4*)s_ov;
  for (int idx = t; idx < KQ / 4; idx += 256)
    __builtin_nontemporal_store(sv4[idx], &ov4[idx]);

  // waves 1-3: default-fill this block's slice (overlaps wave-0 tail)
  if (wid != 0) { zfill(out, gt_bboxes, sbase + (t - 64), sbase + S4, 192); return; }

  const int n = s_cnt;

  // fast path: n <= 15 candidates -> emit all, no selection needed.
  // candk slot order is irrelevant: kA2's merge extracts by key max, and all
  // downstream results depend only on the key-ordered set (deterministic).
  if (n <= NT) {
    if (lane < NT) {
      unsigned long long key = 0ULL;
      if (lane < n) {
        const int gk = kbeg + s_ci[lane];
        key = ((unsigned long long)__float_as_uint(s_cv[lane]) << 32) |
              (unsigned long long)(0xFFFFFFFFu - (unsigned)gk);
      }
      ck[lane] = key;
    }
    return;
  }

  // slow path: per-quarter top-15 by iterative argmax
  // key = fbits(am)<<32 | (0xFFFF - local_idx); local order == global order
  unsigned long long bkey = 0; int bslot = -1;
  for (int e = lane; e < n; e += 64) {
    float v = s_cv[e];
    unsigned long long key =
        ((unsigned long long)__float_as_uint(v) << 32) |
        (unsigned long long)(0xFFFFu - s_ci[e]);
    if (key > bkey) { bkey = key; bslot = e; }
  }
  for (int it = 0; it < NT; ++it) {
    unsigned long long wkey = bkey;
    #pragma unroll
    for (int d = 1; d < 64; d <<= 1) {
      unsigned long long ok = __shfl_xor(wkey, d);
      if (ok > wkey) wkey = ok;
    }
    if (lane == 0) {
      // re-expand to global-k key for the cross-quarter merge in kA2
      const int gk = kbeg + (int)(0xFFFFu - (unsigned)(wkey & 0xFFFFu));
      ck[it] = (wkey & 0xFFFFFFFF00000000ull) |
               (unsigned long long)(0xFFFFFFFFu - (unsigned)gk);
    }
    if (bkey == wkey) {         // unique winner (local idx unique in low bits)
      s_cv[bslot] = -1.f;
      bkey = 0; bslot = -1;
      for (int e = lane; e < n; e += 64) {
        float v = s_cv[e];
        if (v >= 0.f) {
          unsigned long long key =
              ((unsigned long long)__float_as_uint(v) << 32) |
              (unsigned long long)(0xFFFFu - s_ci[e]);
          if (key > bkey) { bkey = key; bslot = e; }
        }
      }
    }
  }
}

// ---------------------------------------------------------------------------
// kA2: one wave per (b,m): merge 4x15 quarter candidates -> global top-15
// (selection by packed key: value desc, idx asc — order within candk slots
// is irrelevant), fg0/flag atomics, ovmax merge. Kernel boundary provides
// cross-XCD visibility of candk.
// ---------------------------------------------------------------------------
__global__ __launch_bounds__(64) void kA2(
    const unsigned long long* __restrict__ candk,
    const float* __restrict__ ovmaxq, float* __restrict__ ovmaxp,
    int* __restrict__ tki, float* __restrict__ tkv,
    int* __restrict__ fg0, int* __restrict__ flag)
{
  const int bm = blockIdx.x;
  const int b  = bm >> 6;
  const int lane = threadIdx.x;

  if (lane == 0) {
    const float* om = ovmaxq + bm * NQ;
    ovmaxp[bm] = fmaxf(fmaxf(om[0], om[1]), fmaxf(om[2], om[3]));
  }

  unsigned long long mkey = (lane < NQ * NT)
      ? candk[(size_t)bm * NQ * NT + lane] : 0ULL;
  unsigned long long mywin = 0ULL;
  int nf = 0;
  for (int it = 0; it < NT; ++it) {
    unsigned long long wkey = mkey;
    #pragma unroll
    for (int d = 1; d < 64; d <<= 1) {
      unsigned long long ok = __shfl_xor(wkey, d);
      if (ok > wkey) wkey = ok;
    }
    if (wkey == 0) break;
    if (lane == it) mywin = wkey;                // round-it winner kept in lane it
    if (mkey == wkey) mkey = 0ULL;               // unique winner consumed
    nf = it + 1;
  }

  if (lane < NT) {
    if (lane < nf) {
      const int fi = (int)(0xFFFFFFFFu - (unsigned)mywin);
      tki[bm * NT + lane] = fi;
      tkv[bm * NT + lane] = __uint_as_float((unsigned)(mywin >> 32));
      int old = atomicAdd(&fg0[(size_t)b * NK + fi], 1);
      if (old >= 1) atomicOr(flag, 1);
    } else {
      tki[bm * NT + lane] = -1;
      tkv[bm * NT + lane] = 0.f;
    }
  }
}

// ---------------------------------------------------------------------------
// kFS: one wave per (b,m). Keep-filter (mikey + flag), 16-lane rowmax, then
// <=15 scattered writes each of {assign=1, tso=sval, fg=1, tgt=gtb[bm]}.
// Post-filter assignment is unique per k => race-free. Defaults (fg=0,
// tgt=gtb[b][0], tso=0, assign=0) were produced by kAF/kZ fill.
// ---------------------------------------------------------------------------
__global__ __launch_bounds__(64) void kFS(
    const float* __restrict__ gt_bboxes, const int* __restrict__ gt_labels,
    const int* __restrict__ tki, const float* __restrict__ tkv,
    const float* __restrict__ ovmaxp, const unsigned long long* __restrict__ mikey,
    const int* __restrict__ flagp, float* __restrict__ out)
{
  const int bm = blockIdx.x;
  const int b  = bm >> 6;
  const int m  = bm & 63;
  const int lane = threadIdx.x;
  const int flag = *flagp;

  int idx = -1; float v = 0.f; bool keep = false;
  if (lane < NT) {
    idx = tki[bm * NT + lane];
    if (idx >= 0) {
      v = tkv[bm * NT + lane];
      keep = true;
      if (flag) {
        unsigned long long key = mikey[(size_t)b * NK + idx];
        keep = (NM - 1 - (int)(key & 0xFFFFFFFFull)) == m;   // key>0 for valid
      }
    }
  }
  // post-filter row max of am (reduce over the 16-lane group holding lanes 0-14)
  float r = keep ? v : 0.f;
  #pragma unroll
  for (int d = 1; d < 16; d <<= 1) r = fmaxf(r, __shfl_xor(r, d));

  if (keep) {
    const float sval = v / (r + 1e-9f) * ovmaxp[bm];   // same op order as before
    out[OUT_ASN + (size_t)(b * NM + m) * NK + idx] = 1.f;
    out[OUT_TSO + (size_t)(b * NK + idx) * NC + gt_labels[bm]] = sval;
    out[OUT_FG + (size_t)b * NK + idx] = 1.f;
    *(f32x4*)(out + OUT_TGT + (size_t)(b * NK + idx) * 4) =
        *(const f32x4*)(gt_bboxes + (size_t)bm * 4);
  }
}

// ---------------------------------------------------------------------------
extern "C" void kernel_launch(void* const* d_in, const int* in_sizes, int n_in,
                              void* d_out, int out_size, void* d_ws, size_t ws_size,
                              hipStream_t stream)
{
  const float* points      = (const float*)d_in[0];
  const float* gt_bboxes   = (const float*)d_in[1];
  const int*   gt_labels   = (const int*)d_in[2];
  const float* pred_bboxes = (const float*)d_in[3];
  const float* pred_scores = (const float*)d_in[4];
  const int*   gt_mask     = (const int*)d_in[5];
  float* out = (float*)d_out;

  char* ws = (char*)d_ws;
  unsigned long long* mikey = (unsigned long long*)ws; ws += (size_t)NB * NK * 8;
  int*   fg0    = (int*)ws;    ws += (size_t)NB * NK * 4;
  int*   flag   = (int*)ws;    ws += 256;
  unsigned long long* candk = (unsigned long long*)ws;
                               ws += (size_t)NB * NM * NQ * NT * 8;
  int*   tki    = (int*)ws;    ws += (size_t)NB * NM * NT * 4;
  float* tkv    = (float*)ws;  ws += (size_t)NB * NM * NT * 4;
  float* ovmaxp = (float*)ws;  ws += (size_t)NB * NM * 4;
  float* ovmaxq = (float*)ws;  ws += (size_t)NB * NM * NQ * 4;

  // ws init + residual fill (must precede kAF's mikey atomics)
  kZ<<<1024, 256, 0, stream>>>(out, gt_bboxes, mikey, fg0, flag);

  // fused default-fill + compute (uniform blocks, no cross-block sync)
  kAF<<<NCOMP, 256, 0, stream>>>(points, gt_bboxes, gt_labels,
                                 pred_bboxes, pred_scores, gt_mask,
                                 out, candk, ovmaxq, mikey);

  kA2<<<NB * NM, 64, 0, stream>>>(candk, ovmaxq, ovmaxp, tki, tkv, fg0, flag);

  kFS<<<NB * NM, 64, 0, stream>>>(gt_bboxes, gt_labels, tki, tkv, ovmaxp,
                                  mikey, flag, out);
}

// Round 18
// 77.718 us; speedup vs baseline: 1.0369x; 1.0348x over previous
//
#include <hip/hip_runtime.h>
#include <math.h>

// Problem constants (match reference)
constexpr int NB = 32, NM = 64, NK = 8400, NC = 80, NT = 15;
constexpr int NQ = 4, KQ = 2100;       // k split into 4 quarters of 2100
constexpr float FEPS = 1e-7f;

typedef float f32x4 __attribute__((ext_vector_type(4)));   // NT-store compatible

// Output layout: [tso | tgt_bboxes | assign | overlaps | fg], all float32
constexpr size_t OUT_TSO = 0;
constexpr size_t OUT_TGT = (size_t)NB * NK * NC;            // 21504000
constexpr size_t OUT_ASN = OUT_TGT + (size_t)NB * NK * 4;   // 22579200
constexpr size_t OUT_OVL = OUT_ASN + (size_t)NB * NM * NK;  // 39782400
constexpr size_t OUT_FG  = OUT_OVL + (size_t)NB * NM * NK;  // 56985600

constexpr int NCOMP = NB * NM * NQ;    // 8192 compute blocks
constexpr int NFILL = 2048;            // fill blocks (every 5th block)
constexpr int N4A  = (int)(OUT_TGT / 4);   // tso end (f32x4 units)
constexpr int ASN4 = (int)(OUT_ASN / 4);   // tgt end / assign begin
constexpr int OVL4 = (int)(OUT_OVL / 4);   // assign end (tso+tgt+asn span)
constexpr int FG4s = (int)(OUT_FG / 4);    // fg begin
constexpr int FG4c = NB * NK / 4;          // fg count = 67200
constexpr int TOT4 = OVL4 + FG4c;          // 10,012,800 f32x4 to default-fill
constexpr int S4   = 960;                  // slice per compute block
constexpr int F4   = TOT4 - NCOMP * S4;    // 2,148,480 for fill blocks

// default-fill: tso=0, tgt=gtb[b][0] (argmax of all-zero col -> 0), asn=0, fg=0
static __device__ __forceinline__ void zfill(float* out,
                                             const float* __restrict__ gtb,
                                             int j0, int j1, int step)
{
  f32x4* o4 = (f32x4*)out;
  const f32x4 z = {0.f, 0.f, 0.f, 0.f};
  for (int j = j0; j < j1; j += step) {
    const int a = (j < OVL4) ? j : FG4s + (j - OVL4);
    f32x4 v = z;
    if (a >= N4A && a < ASN4)        // tgt region: one f32x4 per (b,k)
      v = *(const f32x4*)(gtb + (size_t)((a - N4A) / NK) * NM * 4);
    __builtin_nontemporal_store(v, &o4[a]);
  }
}

// ---------------------------------------------------------------------------
// kZ: workspace init (mikey=0, fg0=0, flag=0). Must precede kAF (atomicMax).
// ---------------------------------------------------------------------------
__global__ __launch_bounds__(256) void kZ(unsigned long long* __restrict__ mikey,
                                          int* __restrict__ fg0,
                                          int* __restrict__ flag)
{
  const int n = NB * NK;
  const int tid = blockIdx.x * 256 + threadIdx.x;
  for (int i = tid; i < n; i += gridDim.x * 256) { mikey[i] = 0ULL; fg0[i] = 0; }
  if (tid == 0) *flag = 0;
}

// ---------------------------------------------------------------------------
// kAF: 10240 blocks, role-specialized (every 5th = fill, rest = compute).
// NO device fences / cross-block sync — visibility via kernel boundary.
//  fill   : streaming NT default-fill (tso/asn/fg zeros + tgt=gtb[b][0])
//  compute: one block per (b,m,quarter):
//    pass 1: zero LDS ov tile + point-in-box -> ushort positive list
//    pass 2: CIoU on positives -> s_ov, mi atomicMax key, (am,idx) candidates
//    flush : dense f32x4 NT overlaps write from s_ov
//    tail  : wave 0 emits per-quarter top-15 -> candk (n<=15: direct write,
//            order-free for kA2's key-max merge) WHILE waves 1-3 default-fill
//            this block's 15 KB slice (store-issue overlap)
// ---------------------------------------------------------------------------
__global__ __launch_bounds__(256) void kAF(
    const float* __restrict__ points, const float* __restrict__ gt_bboxes,
    const int* __restrict__ gt_labels, const float* __restrict__ pred_bboxes,
    const float* __restrict__ pred_scores, const int* __restrict__ gt_mask,
    float* __restrict__ out, unsigned long long* __restrict__ candk,
    float* __restrict__ ovmaxq, unsigned long long* __restrict__ mikey)
{
  __shared__ __align__(16) float s_ov[KQ];       // 8.4 KB dense overlaps tile
  __shared__ unsigned short s_pos[KQ];           // 4.2 KB positive local-idx list
  __shared__ float s_cv[KQ];                     // 8.4 KB candidate am values
  __shared__ unsigned short s_ci[KQ];            // 4.2 KB candidate local idx
  __shared__ int   s_np, s_cnt;
  __shared__ float s_m[4];

  const int bx = blockIdx.x;
  const int t  = threadIdx.x;

  // ---- fill role: every 5th block default-fills [0, F4) ----
  if ((bx % 5) == 4) {
    zfill(out, gt_bboxes, (bx / 5) * 256 + t, F4, NFILL * 256);
    return;
  }

  // ---- compute role ----
  const int cidx = bx - (bx + 1) / 5;            // 0..8191
  const int bm = cidx >> 2;                      // 4 quarter blocks adjacent
  const int q  = cidx & 3;
  const int b  = bm >> 6;
  const int m  = bm & 63;
  const int wid = t >> 6, lane = t & 63;
  const int kbeg = q * KQ;
  const int sbase = F4 + cidx * S4;              // this block's fill slice

  unsigned long long* ck = candk + (size_t)(bm * NQ + q) * NT;
  float* ovl_out = out + OUT_OVL + (size_t)bm * NK;
  f32x4* ov4 = (f32x4*)(ovl_out + kbeg);

  const int maskv = gt_mask[bm];
  if (!maskv) {
    const f32x4 z = {0.f, 0.f, 0.f, 0.f};
    for (int idx = t; idx < KQ / 4; idx += 256)
      __builtin_nontemporal_store(z, &ov4[idx]);
    if (wid != 0) { zfill(out, gt_bboxes, sbase + (t - 64), sbase + S4, 192); return; }
    if (t == 0) ovmaxq[bm * NQ + q] = 0.f;
    if (lane < NT) ck[lane] = 0ULL;
    return;
  }
  if (t == 0) { s_np = 0; s_cnt = 0; }
  __syncthreads();

  const float4 g = *(const float4*)(gt_bboxes + (size_t)bm * 4);
  const int   label = gt_labels[bm];
  const float2* pts = (const float2*)points;

  // pass 1: zero ov tile + point-in-box (diff.max(-1)<1e-6, exact f32 subs)
  #pragma unroll
  for (int j = 0; j < 9; ++j) {
    const int idx = j * 256 + t;
    if (idx < KQ) {
      s_ov[idx] = 0.f;
      const int k = kbeg + idx;
      float2 p = pts[k];
      float dmax = fmaxf(fmaxf(g.x - p.x, g.y - p.y),
                         fmaxf(p.x - g.z, p.y - g.w));
      if (dmax < 1e-6f) {
        int e = atomicAdd(&s_np, 1);
        s_pos[e] = (unsigned short)idx;
      }
    }
  }
  __syncthreads();
  const int np = s_np;

  const float4* pb = (const float4*)(pred_bboxes + (size_t)b * NK * 4);
  const float*  ps = pred_scores + (size_t)b * NK * NC;
  unsigned long long* mk = mikey + (size_t)b * NK;

  const float w1 = g.z - g.x, h1 = g.w - g.y;
  const float at1 = atanf(w1 / (h1 + FEPS));
  const float area1 = w1 * h1;
  const float CV = (float)(4.0 / (M_PI * M_PI));
  const float ONE_EPS = (float)(1.0 + 1e-7);

  float lmax = 0.f;
  for (int e = t; e < np; e += 256) {
    const int li = s_pos[e];
    const int k = kbeg + li;
    float4 qb = pb[k];
    float w2 = qb.z - qb.x, h2 = qb.w - qb.y;
    float iw = fmaxf(fminf(g.z, qb.z) - fmaxf(g.x, qb.x), 0.f);
    float ih = fmaxf(fminf(g.w, qb.w) - fmaxf(g.y, qb.y), 0.f);
    float inter = iw * ih;
    float uni = area1 + w2 * h2 - inter + FEPS;
    float iou = inter / uni;
    float cw = fmaxf(g.z, qb.z) - fminf(g.x, qb.x);
    float ch = fmaxf(g.w, qb.w) - fminf(g.y, qb.y);
    float c2 = cw * cw + ch * ch + FEPS;
    float ex = qb.x + qb.z - g.x - g.z;
    float ey = qb.y + qb.w - g.y - g.w;
    float rho2 = (ex * ex + ey * ey) * 0.25f;
    float dat = atanf(w2 / (h2 + FEPS)) - at1;
    float v = CV * dat * dat;
    float alpha = v / (v - iou + ONE_EPS);
    float ciou = iou - (rho2 / c2 + alpha * v);
    float ov = fmaxf(ciou, 0.f);
    if (ov > 0.f) {
      s_ov[li] = ov;
      unsigned long long key =
          ((unsigned long long)__float_as_uint(ov) << 32) |
          (unsigned long long)(NM - 1 - m);             // value desc, first-m tie
      atomicMax(&mk[k], key);
      lmax = fmaxf(lmax, ov);
      float ts = ps[(size_t)k * NC + label];
      float o2 = ov * ov;
      float am = ts * (o2 * o2 * o2);                   // ts**1 * ov**6
      if (am > 1e-9f) {                                 // below cutoff never selected
        int p2 = atomicAdd(&s_cnt, 1);
        s_cv[p2] = am;
        s_ci[p2] = (unsigned short)li;
      }
    }
  }

  // partial row-max of overlaps
  float mv = lmax;
  #pragma unroll
  for (int d = 1; d < 64; d <<= 1) mv = fmaxf(mv, __shfl_xor(mv, d));
  if (lane == 0) s_m[wid] = mv;
  __syncthreads();   // finalizes s_ov, s_cv/s_ci, s_m
  if (t == 0)
    ovmaxq[bm * NQ + q] = fmaxf(fmaxf(s_m[0], s_m[1]), fmaxf(s_m[2], s_m[3]));

  // dense coalesced overlaps flush (zeros + positives)
  const f32x4* sv4 = (const f32x4*)s_ov;
  for (int idx = t; idx < KQ / 4; idx += 256)
    __builtin_nontemporal_store(sv4[idx], &ov4[idx]);

  // waves 1-3: default-fill this block's slice (overlaps wave-0 tail)
  if (wid != 0) { zfill(out, gt_bboxes, sbase + (t - 64), sbase + S4, 192); return; }

  const int n = s_cnt;

  // fast path: n <= 15 candidates -> emit all, no selection needed.
  // candk slot order is irrelevant: kA2's merge extracts by key max, and all
  // downstream results depend only on the key-ordered set (deterministic).
  if (n <= NT) {
    if (lane < NT) {
      unsigned long long key = 0ULL;
      if (lane < n) {
        const int gk = kbeg + s_ci[lane];
        key = ((unsigned long long)__float_as_uint(s_cv[lane]) << 32) |
              (unsigned long long)(0xFFFFFFFFu - (unsigned)gk);
      }
      ck[lane] = key;
    }
    return;
  }

  // slow path: per-quarter top-15 by iterative argmax
  // key = fbits(am)<<32 | (0xFFFF - local_idx); local order == global order
  unsigned long long bkey = 0; int bslot = -1;
  for (int e = lane; e < n; e += 64) {
    float v = s_cv[e];
    unsigned long long key =
        ((unsigned long long)__float_as_uint(v) << 32) |
        (unsigned long long)(0xFFFFu - s_ci[e]);
    if (key > bkey) { bkey = key; bslot = e; }
  }
  for (int it = 0; it < NT; ++it) {
    unsigned long long wkey = bkey;
    #pragma unroll
    for (int d = 1; d < 64; d <<= 1) {
      unsigned long long ok = __shfl_xor(wkey, d);
      if (ok > wkey) wkey = ok;
    }
    if (lane == 0) {
      // re-expand to global-k key for the cross-quarter merge in kA2
      const int gk = kbeg + (int)(0xFFFFu - (unsigned)(wkey & 0xFFFFu));
      ck[it] = (wkey & 0xFFFFFFFF00000000ull) |
               (unsigned long long)(0xFFFFFFFFu - (unsigned)gk);
    }
    if (bkey == wkey) {         // unique winner (local idx unique in low bits)
      s_cv[bslot] = -1.f;
      bkey = 0; bslot = -1;
      for (int e = lane; e < n; e += 64) {
        float v = s_cv[e];
        if (v >= 0.f) {
          unsigned long long key =
              ((unsigned long long)__float_as_uint(v) << 32) |
              (unsigned long long)(0xFFFFu - s_ci[e]);
          if (key > bkey) { bkey = key; bslot = e; }
        }
      }
    }
  }
}

// ---------------------------------------------------------------------------
// kA2: one wave per (b,m): merge 4x15 quarter candidates -> global top-15
// (selection by packed key: value desc, idx asc — order within candk slots
// is irrelevant), fg0/flag atomics, ovmax merge. Kernel boundary provides
// cross-XCD visibility of candk.
// ---------------------------------------------------------------------------
__global__ __launch_bounds__(64) void kA2(
    const unsigned long long* __restrict__ candk,
    const float* __restrict__ ovmaxq, float* __restrict__ ovmaxp,
    int* __restrict__ tki, float* __restrict__ tkv,
    int* __restrict__ fg0, int* __restrict__ flag)
{
  const int bm = blockIdx.x;
  const int b  = bm >> 6;
  const int lane = threadIdx.x;

  if (lane == 0) {
    const float* om = ovmaxq + bm * NQ;
    ovmaxp[bm] = fmaxf(fmaxf(om[0], om[1]), fmaxf(om[2], om[3]));
  }

  unsigned long long mkey = (lane < NQ * NT)
      ? candk[(size_t)bm * NQ * NT + lane] : 0ULL;
  unsigned long long mywin = 0ULL;
  int nf = 0;
  for (int it = 0; it < NT; ++it) {
    unsigned long long wkey = mkey;
    #pragma unroll
    for (int d = 1; d < 64; d <<= 1) {
      unsigned long long ok = __shfl_xor(wkey, d);
      if (ok > wkey) wkey = ok;
    }
    if (wkey == 0) break;
    if (lane == it) mywin = wkey;                // round-it winner kept in lane it
    if (mkey == wkey) mkey = 0ULL;               // unique winner consumed
    nf = it + 1;
  }

  if (lane < NT) {
    if (lane < nf) {
      const int fi = (int)(0xFFFFFFFFu - (unsigned)mywin);
      tki[bm * NT + lane] = fi;
      tkv[bm * NT + lane] = __uint_as_float((unsigned)(mywin >> 32));
      int old = atomicAdd(&fg0[(size_t)b * NK + fi], 1);
      if (old >= 1) atomicOr(flag, 1);
    } else {
      tki[bm * NT + lane] = -1;
      tkv[bm * NT + lane] = 0.f;
    }
  }
}

// ---------------------------------------------------------------------------
// kFS: one wave per (b,m). Keep-filter (mikey + flag), 16-lane rowmax, then
// <=15 scattered writes each of {assign=1, tso=sval, fg=1, tgt=gtb[bm]}.
// Post-filter assignment is unique per k => race-free. Defaults (fg=0,
// tgt=gtb[b][0], tso=0, assign=0) were produced by kAF's fill.
// ---------------------------------------------------------------------------
__global__ __launch_bounds__(64) void kFS(
    const float* __restrict__ gt_bboxes, const int* __restrict__ gt_labels,
    const int* __restrict__ tki, const float* __restrict__ tkv,
    const float* __restrict__ ovmaxp, const unsigned long long* __restrict__ mikey,
    const int* __restrict__ flagp, float* __restrict__ out)
{
  const int bm = blockIdx.x;
  const int b  = bm >> 6;
  const int m  = bm & 63;
  const int lane = threadIdx.x;
  const int flag = *flagp;

  int idx = -1; float v = 0.f; bool keep = false;
  if (lane < NT) {
    idx = tki[bm * NT + lane];
    if (idx >= 0) {
      v = tkv[bm * NT + lane];
      keep = true;
      if (flag) {
        unsigned long long key = mikey[(size_t)b * NK + idx];
        keep = (NM - 1 - (int)(key & 0xFFFFFFFFull)) == m;   // key>0 for valid
      }
    }
  }
  // post-filter row max of am (reduce over the 16-lane group holding lanes 0-14)
  float r = keep ? v : 0.f;
  #pragma unroll
  for (int d = 1; d < 16; d <<= 1) r = fmaxf(r, __shfl_xor(r, d));

  if (keep) {
    const float sval = v / (r + 1e-9f) * ovmaxp[bm];   // same op order as before
    out[OUT_ASN + (size_t)(b * NM + m) * NK + idx] = 1.f;
    out[OUT_TSO + (size_t)(b * NK + idx) * NC + gt_labels[bm]] = sval;
    out[OUT_FG + (size_t)b * NK + idx] = 1.f;
    *(f32x4*)(out + OUT_TGT + (size_t)(b * NK + idx) * 4) =
        *(const f32x4*)(gt_bboxes + (size_t)bm * 4);
  }
}

// ---------------------------------------------------------------------------
extern "C" void kernel_launch(void* const* d_in, const int* in_sizes, int n_in,
                              void* d_out, int out_size, void* d_ws, size_t ws_size,
                              hipStream_t stream)
{
  const float* points      = (const float*)d_in[0];
  const float* gt_bboxes   = (const float*)d_in[1];
  const int*   gt_labels   = (const int*)d_in[2];
  const float* pred_bboxes = (const float*)d_in[3];
  const float* pred_scores = (const float*)d_in[4];
  const int*   gt_mask     = (const int*)d_in[5];
  float* out = (float*)d_out;

  char* ws = (char*)d_ws;
  unsigned long long* mikey = (unsigned long long*)ws; ws += (size_t)NB * NK * 8;
  int*   fg0    = (int*)ws;    ws += (size_t)NB * NK * 4;
  int*   flag   = (int*)ws;    ws += 256;
  unsigned long long* candk = (unsigned long long*)ws;
                               ws += (size_t)NB * NM * NQ * NT * 8;
  int*   tki    = (int*)ws;    ws += (size_t)NB * NM * NT * 4;
  float* tkv    = (float*)ws;  ws += (size_t)NB * NM * NT * 4;
  float* ovmaxp = (float*)ws;  ws += (size_t)NB * NM * 4;
  float* ovmaxq = (float*)ws;  ws += (size_t)NB * NM * NQ * 4;

  // ws init (must precede kAF's mikey atomics)
  kZ<<<1024, 256, 0, stream>>>(mikey, fg0, flag);

  // fused default-fill + compute (no cross-block sync inside)
  kAF<<<NCOMP + NFILL, 256, 0, stream>>>(points, gt_bboxes, gt_labels,
                                         pred_bboxes, pred_scores, gt_mask,
                                         out, candk, ovmaxq, mikey);

  kA2<<<NB * NM, 64, 0, stream>>>(candk, ovmaxq, ovmaxp, tki, tkv, fg0, flag);

  kFS<<<NB * NM, 64, 0, stream>>>(gt_bboxes, gt_labels, tki, tkv, ovmaxp,
                                  mikey, flag, out);
}